// Round 6
// baseline (2089.988 us; speedup 1.0000x reference)
//
#include <hip/hip_runtime.h>
#include <stdint.h>

typedef __bf16 bf16x8 __attribute__((ext_vector_type(8)));
typedef float  f32x4  __attribute__((ext_vector_type(4)));
typedef unsigned short u16;
typedef unsigned int   u32;

#define NN   4096      // nodes
#define KCH  16        // max children
#define RR   8192      // rows in h/c tensors

// ---------------- workspace layout (bytes) ----------------
static constexpr size_t OFF_WCOMB = 0;          //  8 gd x 1024 pc x 512 k bf16 (k<256 rec^T, k>=256 kernel^T; pc perm gate=pc&3,unit=pc>>2)
static constexpr size_t OFF_FCWT  = 8388608;    //  4 g x 256 o x 768 k bf16 (k<512 fc_w^T, k>=512 W_w gate-block g)
static constexpr size_t OFF_YSEQ  = 9961472;    //  2 d x (4096 n x 16 t) x 256 u bf16 (sorted n)
static constexpr size_t OFF_YLAST = 77070336;   //  8 gd x 4096 n x 256 u bf16 (sorted, gd>=2 used)
static constexpr size_t OFF_BRF   = 93847552;   //  4096 x 256 bf16 (sorted)
static constexpr size_t OFF_FCO   = 95944704;   //  3 x 4096 x 256 bf16 (sorted)
static constexpr size_t OFF_XS    = 102236160;  //  4096 x 256 bf16 (x in sorted order)
static constexpr size_t OFF_HN    = 104333312;  //  8192 x 256 bf16 (normalized h_tensor)
static constexpr size_t OFF_CN    = 108527616;  //  8192 x 256 bf16 (normalized c_tensor)
static constexpr size_t OFF_BIASN = 112721920;  //  8 gd x 1024 pc bf16
static constexpr size_t OFF_IHN   = 112738304;  //  8 x 256 bf16
static constexpr size_t OFF_ICN   = 112742400;  //  8 x 256 bf16
static constexpr size_t OFF_WBN   = 112746496;  //  1024 bf16
static constexpr size_t OFF_IDX   = 112748544;  //  [16 t][4096 sorted n] int32 (safe fwd child idx)
static constexpr size_t OFF_LEN   = 113010688;  //  4096 int32 (orig order)
static constexpr size_t OFF_FLAG  = 113027072;  //  int
static constexpr size_t OFF_NODEOF= 113027136;  //  4096 int32: sorted pos -> orig node
static constexpr size_t OFF_LENS  = 113043520;  //  4096 int32: len in sorted order
static constexpr size_t WS_NEEDED = 113059904;  //  ~113 MB, known to fit

struct KParams {
  const void *x, *h_tensor, *c_tensor, *W_w, *W_b, *lstm_kernel, *lstm_rec,
             *lstm_bias, *init_h, *init_c, *fc_w;
  const int *indice;
  u16 *wcomb, *fcwT2, *y_seq, *y_last, *brf, *fc_outb,
      *xs, *hn, *cn, *biasn, *inithn, *initcn, *wbn;
  int *idxf, *len, *flag, *nodeof, *len_s;
  float *outp;                       // OUTPUT IS FLOAT32 (established round 3)
};

__device__ __forceinline__ float b2f(u16 u){ union{u32 i;float f;}v; v.i=((u32)u)<<16; return v.f; }
__device__ __forceinline__ u16  f2b(float f){ union{float f;u32 i;}v; v.f=f; u32 r=v.i+0x7FFFu+((v.i>>16)&1u); return (u16)(r>>16); }
__device__ __forceinline__ float sigm(float x){ return 1.0f/(1.0f+__expf(-x)); }
__device__ __forceinline__ float tanh_(float x){ return 2.0f/(1.0f+__expf(-2.0f*x)) - 1.0f; }
__device__ __forceinline__ u16  cvt(const void* q, size_t i, int isf){
  return isf ? f2b(((const float*)q)[i]) : ((const u16*)q)[i];
}
__device__ __forceinline__ void cp16(const u16* g, u16* l){
  __builtin_amdgcn_global_load_lds((const __attribute__((address_space(1))) u32*)g,
                                   (__attribute__((address_space(3))) u32*)l, 16, 0, 0);
}

// ---------------- dtype detector (fp32 vs bf16 inputs) ----------------
__global__ void detect_k(KParams p){
  __shared__ int cnt[256];
  int tid = threadIdx.x;
  u16 u = ((const u16*)p.x)[2*tid];
  int e = (u >> 7) & 0xFF;
  cnt[tid] = (u != 0 && e >= 100 && e <= 140) ? 1 : 0;
  __syncthreads();
  if (tid == 0){
    int s = 0;
    for (int i=0;i<256;i++) s += cnt[i];
    *p.flag = (s < 192) ? 1 : 0;   // 1 = fp32 inputs
  }
}

// ---------------- prep kernels ----------------
__global__ void prep_idx_k(KParams p){
  int n = blockIdx.x*256 + threadIdx.x;
  if (n >= NN) return;
  int L = 0;
  #pragma unroll
  for (int t=0;t<KCH;t++) L += (p.indice[n*KCH+t] != -1);
  p.len[n] = L;
}

// counting sort by L descending
__global__ void sort_k(KParams p){
  __shared__ int cnt[17];
  __shared__ int start[17];
  int tid = threadIdx.x;
  if (tid < 17) cnt[tid] = 0;
  __syncthreads();
  for (int n = tid; n < NN; n += 256) atomicAdd(&cnt[p.len[n]], 1);
  __syncthreads();
  if (tid == 0){
    int acc = 0;
    for (int v = 16; v >= 1; --v){ start[v] = acc; acc += cnt[v]; }
  }
  __syncthreads();
  for (int n = tid; n < NN; n += 256){
    int ps = atomicAdd(&start[p.len[n]], 1);
    p.nodeof[ps] = n;
  }
}

__global__ void norm_k(KParams p){
  int i = blockIdx.x*256 + threadIdx.x;
  if (i >= 4207616) return;
  int isf = *p.flag;
  if (i < 2097152)       p.hn[i] = cvt(p.h_tensor, i, isf);
  else if (i < 4194304)  p.cn[i-2097152] = cvt(p.c_tensor, i-2097152, isf);
  else if (i < 4202496){ int j = i-4194304; int gd = j>>10, pc = j&1023;
                         p.biasn[j] = cvt(p.lstm_bias, gd*1024 + ((pc&3)<<8) + (pc>>2), isf); }
  else if (i < 4204544)  p.inithn[i-4202496] = cvt(p.init_h, i-4202496, isf);
  else if (i < 4206592)  p.initcn[i-4204544] = cvt(p.init_c, i-4204544, isf);
  else                   p.wbn[i-4206592] = cvt(p.W_b, i-4206592, isf);
}

__global__ void xperm_k(KParams p){      // xs[sorted] = x[orig]
  int ns = blockIdx.x, u = threadIdx.x;
  int n = p.nodeof[ns];
  p.xs[(size_t)ns*256 + u] = cvt(p.x, (size_t)n*256 + u, *p.flag);
}

__global__ void prep_idx2_k(KParams p){  // idxf/len_s in sorted space
  int ns = blockIdx.x*256 + threadIdx.x;
  if (ns >= NN) return;
  int n = p.nodeof[ns];
  p.len_s[ns] = p.len[n];
  #pragma unroll
  for (int t=0;t<KCH;t++){
    int v = p.indice[n*KCH+t];
    p.idxf[t*NN + ns] = (v != -1) ? v : 0;
  }
}

__global__ void prep_w_k(KParams p){
  int i = blockIdx.x*256 + threadIdx.x;
  int isf = *p.flag;
  if (i < 4194304){                       // wcomb [gd][pc][k]
    int gd = i>>19, pc = (i>>9)&1023, k = i&511;
    int perm = ((pc&3)<<8) + (pc>>2);
    p.wcomb[i] = (k < 256) ? cvt(p.lstm_rec,    (size_t)(gd*256 + k)*1024 + perm, isf)
                           : cvt(p.lstm_kernel, (size_t)(gd*256 + (k-256))*1024 + perm, isf);
  } else if (i < 4980736){                // fcwT2 [g][o][k], k<512 fc_w, k>=512 W_w
    int j = i - 4194304;
    int g = j/196608, rem = j%196608, o = rem/768, k = rem%768;
    p.fcwT2[j] = (k < 512) ? cvt(p.fc_w, (size_t)(g*512 + k)*256 + o, isf)
                           : cvt(p.W_w,  (size_t)(k-512)*1024 + g*256 + o, isf);
  }
}

__global__ void fallback_k(float* out){
  int i = blockIdx.x*256 + threadIdx.x;
  out[i] = 1000.0f; out[1048576 + i] = 1000.0f;
}

// ---------------- persistent stage kernel ----------------
// block = (gd, 64 sorted nodes). h-state in LDS (XOR-chunk swizzled), c-state
// in regs, gather staged per stage, A (wcomb) global->VGPR (L2 resident).
__device__ __forceinline__ void flushy(const KParams& p, int gd, int d, int nbase,
                                       int tp, const u16* hS, int tid){
  int row = tid >> 2, part = tid & 3;
  int ng = nbase + row;
  if (gd < 2){
    u16* dst = p.y_seq + ((size_t)d*65536 + (size_t)ng*16 + tp)*256;
    #pragma unroll
    for (int j = 0; j < 8; ++j){
      int cl = part*8 + j;
      uint4 v = *(const uint4*)&hS[row*256 + ((cl ^ (row&7))<<3)];
      *(uint4*)(dst + cl*8) = v;
    }
  } else if (p.len_s[ng] == tp+1){
    u16* dst = p.y_last + ((size_t)gd*NN + ng)*256;
    #pragma unroll
    for (int j = 0; j < 8; ++j){
      int cl = part*8 + j;
      uint4 v = *(const uint4*)&hS[row*256 + ((cl ^ (row&7))<<3)];
      *(uint4*)(dst + cl*8) = v;
    }
  }
}

__global__ __launch_bounds__(256, 2) void stage_persist_k(KParams p){
  __shared__ __align__(16) u16 hS[16384];   // [64 n][256 u], chunk-XOR swizzled
  __shared__ __align__(16) u16 gS[16384];   // [64 n][256 k], chunk-XOR swizzled

  const int b = blockIdx.x;
  const int gd = b & 7, ntile = b >> 3;     // gd fastest -> XCD-pinned
  const int nbase = ntile * 64;
  const int tid = threadIdx.x, lane = tid & 63, wv = tid >> 6;
  const int col16 = lane & 15, quad = lane >> 4;
  const int d = gd & 1;
  const u16* __restrict__ wc = p.wcomb + (size_t)gd * 524288;
  const int Lmax = p.len_s[nbase];          // sorted desc -> tile max

  // ownership: tile flat i = pI*16 + mf*4 + nf:
  //   u = wv*64 + pI*16 + mf*4 + quad ; n = nf*16 + col16
  float c_reg[64];
  u16   h_reg[64];
  {
    const u16* ih = p.inithn + gd*256;
    const u16* ic = p.initcn + gd*256;
    #pragma unroll
    for (int i = 0; i < 64; ++i){
      int u = wv*64 + (i>>4)*16 + ((i>>2)&3)*4 + quad;
      h_reg[i] = ih[u];
      c_reg[i] = b2f(ic[u]);
    }
  }

  for (int t = 0; t < Lmax; ++t){
    __syncthreads();                        // prior-stage LDS reads done
    // stage gather (child h rows) via global_load_lds, source-XOR swizzle
    {
      #pragma unroll
      for (int q = 0; q < 8; ++q){
        int ii = wv*8 + q;                  // 32 x 1KB instrs over 4 waves
        int nl = ii*2 + (lane>>5);
        int ng = nbase + nl;
        int L  = p.len_s[ng];
        int eff = (d && t < L) ? (L-1-t) : t;
        int g  = p.idxf[eff*NN + ng];
        int c  = lane & 31;
        cp16(p.hn + (size_t)g*256 + ((c ^ (nl & 7)) << 3), &gS[ii*512]);
      }
    }
    // write h regs -> hS (swizzled scatter)
    #pragma unroll
    for (int i = 0; i < 64; ++i){
      int u = wv*64 + (i>>4)*16 + ((i>>2)&3)*4 + quad;
      int n = (i & 3)*16 + col16;
      hS[n*256 + ((((u>>3) ^ (n & 7)) << 3) | (u & 7))] = h_reg[i];
    }
    __syncthreads();
    if (t > 0) flushy(p, gd, d, nbase, t-1, hS, tid);  // overlapped with k-loop

    #pragma unroll
    for (int pI = 0; pI < 4; ++pI){
      const int mb = wv*256 + pI*64;
      f32x4 acc[4][4] = {};
      for (int kt = 0; kt < 8; ++kt){
        const u16* bs = (kt < 4) ? hS : gS;
        const int ktl = kt & 3;
        #pragma unroll
        for (int ks = 0; ks < 2; ++ks){
          bf16x8 af[4], bfr[4];
          #pragma unroll
          for (int mf = 0; mf < 4; ++mf)
            af[mf] = *(const bf16x8*)(wc + (size_t)(mb + mf*16 + col16)*512 + kt*64 + ks*32 + quad*8);
          #pragma unroll
          for (int nf = 0; nf < 4; ++nf){
            int n  = nf*16 + col16;
            int ch = ktl*8 + ks*4 + quad;
            bfr[nf] = *(const bf16x8*)&bs[n*256 + ((ch ^ (n & 7)) << 3)];
          }
          #pragma unroll
          for (int mf = 0; mf < 4; ++mf)
            #pragma unroll
            for (int nf = 0; nf < 4; ++nf)
              acc[mf][nf] = __builtin_amdgcn_mfma_f32_16x16x32_bf16(af[mf], bfr[nf], acc[mf][nf], 0, 0, 0);
        }
      }
      // LSTM cell epilogue (per lane: 4 regs = gates i,f,g,o of one unit)
      #pragma unroll
      for (int mf = 0; mf < 4; ++mf){
        int pcol = mb + mf*16 + quad*4;
        uint2 bv = *(const uint2*)(p.biasn + gd*1024 + pcol);
        float bi_ = b2f((u16)(bv.x & 0xffffu));
        float bf_ = b2f((u16)(bv.x >> 16));
        float bg_ = b2f((u16)(bv.y & 0xffffu));
        float bo_ = b2f((u16)(bv.y >> 16));
        #pragma unroll
        for (int nf = 0; nf < 4; ++nf){
          int flat = pI*16 + mf*4 + nf;
          float zi = acc[mf][nf][0] + bi_;
          float zf = acc[mf][nf][1] + bf_;
          float zg = acc[mf][nf][2] + bg_;
          float zo = acc[mf][nf][3] + bo_;
          float cp_ = c_reg[flat];
          float cn = sigm(zf)*cp_ + sigm(zi)*tanh_(zg);
          c_reg[flat] = cn;
          h_reg[flat] = f2b(sigm(zo)*tanh_(cn));
        }
      }
    }
  }
  // final: commit last h and flush y(Lmax-1)
  __syncthreads();
  #pragma unroll
  for (int i = 0; i < 64; ++i){
    int u = wv*64 + (i>>4)*16 + ((i>>2)&3)*4 + quad;
    int n = (i & 3)*16 + col16;
    hS[n*256 + ((((u>>3) ^ (n & 7)) << 3) | (u & 7))] = h_reg[i];
  }
  __syncthreads();
  flushy(p, gd, d, nbase, Lmax-1, hS, tid);
}

// ---------------- FC GEMMs (128x128 tile, bf16 MFMA) ----------------
enum { MODE_FC0=0, MODE_FC123=1 };

template<int MODE>
__launch_bounds__(256)
__global__ void gemm_k(KParams p)
{
  __shared__ __align__(16) u16 As[128*64];
  __shared__ __align__(16) u16 Bs[128*64];
  __shared__ int nidx[(MODE==MODE_FC0)?128:1];
  __shared__ int Ln[(MODE==MODE_FC0)?8:1];

  const int tid = threadIdx.x;
  const int lane = tid & 63, wv = tid >> 6;
  const int col16 = lane & 15, quad = lane >> 4;
  const int wy = wv >> 1, wx = wv & 1;

  constexpr int K = 768;

  int mtile = blockIdx.x, ntile = blockIdx.y, gd = blockIdx.z;
  const int rowA = mtile*128;
  const int rowB = ntile*128;

  if constexpr (MODE==MODE_FC0){
    if (tid < 128){
      int nl = tid>>4, tt = tid&15;
      nidx[tid] = p.idxf[tt*NN + mtile*8 + nl];
    }
    if (tid < 8) Ln[tid] = p.len_s[mtile*8 + tid];
    __syncthreads();
  }

  f32x4 acc[4][4] = {};

  for (int kt = 0; kt < K/64; ++kt){
    const int kk = kt*64;
    #pragma unroll
    for (int i=0;i<4;i++){
      int ch = wv*4 + i;
      int r  = ch*8 + (lane>>3);
      int cb = (lane&7)*8;
      const u16 *ga, *gb;
      if constexpr (MODE==MODE_FC0){
        if (kk < 512){
          const u16* Asel = (kk < 256) ? p.y_seq : p.y_seq + (size_t)65536*256;
          ga = Asel + (size_t)(rowA+r)*256 + (kk&255) + cb;
        } else {
          ga = p.xs + (size_t)((rowA+r)>>4)*256 + (kk-512) + cb;
        }
        gb = p.fcwT2 + (size_t)(rowB+r)*768 + kk + cb;
      } else {
        int g = gd + 1;
        if (kk < 512){
          const u16* Asel = p.y_last + (size_t)(g*2 + (kk>=256))*NN*256;
          ga = Asel + (size_t)(rowA+r)*256 + (kk&255) + cb;
        } else {
          ga = p.xs + (size_t)(rowA+r)*256 + (kk-512) + cb;
        }
        gb = p.fcwT2 + (size_t)g*196608 + (size_t)(rowB+r)*768 + kk + cb;
      }
      cp16(ga, &As[ch*512]);
      cp16(gb, &Bs[ch*512]);
    }
    __syncthreads();
    #pragma unroll
    for (int ks=0; ks<64; ks+=32){
      bf16x8 af[4], bfr[4];
      #pragma unroll
      for (int mf=0; mf<4; mf++)
        af[mf] = *(const bf16x8*)&As[(wy*64+mf*16+col16)*64 + ks + quad*8];
      #pragma unroll
      for (int nf=0; nf<4; nf++)
        bfr[nf] = *(const bf16x8*)&Bs[(wx*64+nf*16+col16)*64 + ks + quad*8];
      #pragma unroll
      for (int mf=0; mf<4; mf++)
        #pragma unroll
        for (int nf=0; nf<4; nf++)
          acc[mf][nf] = __builtin_amdgcn_mfma_f32_16x16x32_bf16(af[mf], bfr[nf], acc[mf][nf], 0, 0, 0);
    }
    __syncthreads();
  }

  if constexpr (MODE==MODE_FC0){
    // acc = f_seq + W_f_x (fused); masked f-branch reduce over t
    #pragma unroll
    for (int mf=0; mf<4; mf++){
      int nl = wy*4 + mf;
      int n  = mtile*8 + nl;
      int L  = Ln[nl];
      #pragma unroll
      for (int nf=0; nf<4; nf++){
        int u = rowB + wx*64 + nf*16 + col16;
        float wb_ = b2f(p.wbn[u]);
        float psum = 0.f;
        #pragma unroll
        for (int r=0;r<4;r++){
          int tt = quad*4 + r;
          if (tt < L){
            int ridx = nidx[nl*16 + tt];
            float cch = b2f(p.cn[(size_t)ridx*256 + u]);
            psum += sigm(acc[mf][nf][r] + wb_) * cch;
          }
        }
        psum += __shfl_xor(psum, 16);
        psum += __shfl_xor(psum, 32);
        if (quad == 0) p.brf[(size_t)n*256 + u] = f2b(psum);
      }
    }
  } else {
    int g = gd + 1;
    #pragma unroll
    for (int mf=0; mf<4; mf++){
      int r0 = rowA + wy*64 + mf*16 + quad*4;
      #pragma unroll
      for (int nf=0; nf<4; nf++){
        int c = rowB + wx*64 + nf*16 + col16;
        float wb_ = b2f(p.wbn[g*256 + c]);
        u16* o = p.fc_outb + (size_t)gd*NN*256 + (size_t)r0*256 + c;
        #pragma unroll
        for (int r=0;r<4;r++) o[(size_t)r*256] = f2b(acc[mf][nf][r] + wb_);
      }
    }
  }
}

// ---------------- final combine (fp32 output, un-permute) ----------------
__global__ void final_k(KParams p){
  int i = blockIdx.x*256 + threadIdx.x;  // i = sorted_n*256+u
  int ns = i >> 8, u = i & 255;
  int n = p.nodeof[ns];
  float bf_ = b2f(p.brf[i]);
  float bi = sigm (b2f(p.fc_outb[i]));
  float bu = tanh_(b2f(p.fc_outb[1048576 + i]));
  float bo = sigm (b2f(p.fc_outb[2097152 + i]));
  float nc = bi*bu + bf_;
  float nh = bo*tanh_(nc);
  p.outp[(size_t)n*256 + u] = nh;
  p.outp[1048576 + (size_t)n*256 + u] = nc;
}

extern "C" void kernel_launch(void* const* d_in, const int* in_sizes, int n_in,
                              void* d_out, int out_size, void* d_ws, size_t ws_size,
                              hipStream_t stream) {
  if (ws_size < WS_NEEDED){
    fallback_k<<<4096, 256, 0, stream>>>((float*)d_out);
    return;
  }
  KParams p;
  p.x          = d_in[0];
  p.h_tensor   = d_in[1];
  p.c_tensor   = d_in[2];
  p.indice     = (const int*)d_in[3];
  p.W_w        = d_in[4];
  p.W_b        = d_in[5];
  p.lstm_kernel= d_in[6];
  p.lstm_rec   = d_in[7];
  p.lstm_bias  = d_in[8];
  p.init_h     = d_in[9];
  p.init_c     = d_in[10];
  p.fc_w       = d_in[11];
  char* w = (char*)d_ws;
  p.wcomb   = (u16*)  (w + OFF_WCOMB);
  p.fcwT2   = (u16*)  (w + OFF_FCWT);
  p.y_seq   = (u16*)  (w + OFF_YSEQ);
  p.y_last  = (u16*)  (w + OFF_YLAST);
  p.brf     = (u16*)  (w + OFF_BRF);
  p.fc_outb = (u16*)  (w + OFF_FCO);
  p.xs      = (u16*)  (w + OFF_XS);
  p.hn      = (u16*)  (w + OFF_HN);
  p.cn      = (u16*)  (w + OFF_CN);
  p.biasn   = (u16*)  (w + OFF_BIASN);
  p.inithn  = (u16*)  (w + OFF_IHN);
  p.initcn  = (u16*)  (w + OFF_ICN);
  p.wbn     = (u16*)  (w + OFF_WBN);
  p.idxf    = (int*)  (w + OFF_IDX);
  p.len     = (int*)  (w + OFF_LEN);
  p.flag    = (int*)  (w + OFF_FLAG);
  p.nodeof  = (int*)  (w + OFF_NODEOF);
  p.len_s   = (int*)  (w + OFF_LENS);
  p.outp    = (float*)d_out;

  detect_k    <<<1,     256, 0, stream>>>(p);
  prep_idx_k  <<<16,    256, 0, stream>>>(p);
  sort_k      <<<1,     256, 0, stream>>>(p);
  norm_k      <<<16436, 256, 0, stream>>>(p);
  xperm_k     <<<4096,  256, 0, stream>>>(p);
  prep_idx2_k <<<16,    256, 0, stream>>>(p);
  prep_w_k    <<<19456, 256, 0, stream>>>(p);

  stage_persist_k<<<512, 256, 0, stream>>>(p);   // all 16 timesteps, one launch

  gemm_k<MODE_FC0>  <<<dim3(512,2,1), 256, 0, stream>>>(p);   // f fc (+W_f_x) + masked reduce
  gemm_k<MODE_FC123><<<dim3(32,2,3),  256, 0, stream>>>(p);   // i,u,o last-step fc (+W_x)

  final_k<<<4096, 256, 0, stream>>>(p);
}

// Round 7
// 908.383 us; speedup vs baseline: 2.3008x; 2.3008x over previous
//
#include <hip/hip_runtime.h>
#include <stdint.h>

typedef __bf16 bf16x8 __attribute__((ext_vector_type(8)));
typedef float  f32x4  __attribute__((ext_vector_type(4)));
typedef unsigned short u16;
typedef unsigned int   u32;

#define NN   4096      // nodes
#define KCH  16        // max children
#define RR   8192      // rows in h/c tensors

// ---------------- workspace layout (bytes) ----------------
static constexpr size_t OFF_WCOMB = 0;          //  8 gd x 1024 pc x 512 k bf16
static constexpr size_t OFF_FCWT  = 8388608;    //  4 g x 256 o x 768 k bf16
static constexpr size_t OFF_HST   = 9961472;    //  2 buf x 8 gd x 4096 n x 256 u bf16 (sorted n)
static constexpr size_t OFF_CST   = 43515904;   //  8 gd x 256 u x 4096 n fp32 (sorted)
static constexpr size_t OFF_YSEQ  = 77070336;   //  2 d x (4096 n x 16 t) x 256 u bf16 (sorted)
static constexpr size_t OFF_YLAST = 144179200;  //  8 gd x 4096 n x 256 u bf16 (sorted, gd>=2 used)
static constexpr size_t OFF_BRF   = 160956416;  //  4096 x 256 bf16 (sorted)
static constexpr size_t OFF_FCO   = 163053568;  //  3 x 4096 x 256 bf16 (sorted)
static constexpr size_t OFF_XS    = 169345024;  //  4096 x 256 bf16 (sorted)
static constexpr size_t OFF_HN    = 171442176;  //  8192 x 256 bf16
static constexpr size_t OFF_CN    = 175636480;  //  8192 x 256 bf16
static constexpr size_t OFF_BIASN = 179830784;  //  8 gd x 1024 pc bf16
static constexpr size_t OFF_IHN   = 179847168;  //  8 x 256 bf16
static constexpr size_t OFF_ICN   = 179851264;  //  8 x 256 bf16
static constexpr size_t OFF_WBN   = 179855360;  //  1024 bf16
static constexpr size_t OFF_IDX   = 179857408;  //  [16 t][4096 sorted n] int32
static constexpr size_t OFF_LEN   = 180119552;  //  4096 int32 (orig order)
static constexpr size_t OFF_FLAG  = 180135936;  //  int
static constexpr size_t OFF_NODEOF= 180136000;  //  4096 int32
static constexpr size_t OFF_LENS  = 180152384;  //  4096 int32 (sorted)
static constexpr size_t OFF_NTN   = 180168768;  //  16 int32
static constexpr size_t WS_NEEDED = 180168832;  //  <= 180371456 (known to fit)

struct KParams {
  const void *x, *h_tensor, *c_tensor, *W_w, *W_b, *lstm_kernel, *lstm_rec,
             *lstm_bias, *init_h, *init_c, *fc_w;
  const int *indice;
  u16 *wcomb, *fcwT2, *h_state, *y_seq, *y_last, *brf, *fc_outb,
      *xs, *hn, *cn, *biasn, *inithn, *initcn, *wbn;
  float *c_stateT;
  int *idxf, *len, *flag, *nodeof, *len_s, *ntneed;
  float *outp;                       // OUTPUT IS FLOAT32 (established round 3)
};

__device__ __forceinline__ float b2f(u16 u){ union{u32 i;float f;}v; v.i=((u32)u)<<16; return v.f; }
__device__ __forceinline__ u16  f2b(float f){ union{float f;u32 i;}v; v.f=f; u32 r=v.i+0x7FFFu+((v.i>>16)&1u); return (u16)(r>>16); }
__device__ __forceinline__ float sigm(float x){ return 1.0f/(1.0f+__expf(-x)); }
__device__ __forceinline__ float tanh_(float x){ return 2.0f/(1.0f+__expf(-2.0f*x)) - 1.0f; }
__device__ __forceinline__ u16  cvt(const void* q, size_t i, int isf){
  return isf ? f2b(((const float*)q)[i]) : ((const u16*)q)[i];
}
__device__ __forceinline__ void cp16(const u16* g, u16* l){
  __builtin_amdgcn_global_load_lds((const __attribute__((address_space(1))) u32*)g,
                                   (__attribute__((address_space(3))) u32*)l, 16, 0, 0);
}

// ---------------- dtype detector (fp32 vs bf16 inputs) ----------------
__global__ void detect_k(KParams p){
  __shared__ int cnt[256];
  int tid = threadIdx.x;
  u16 u = ((const u16*)p.x)[2*tid];
  int e = (u >> 7) & 0xFF;
  cnt[tid] = (u != 0 && e >= 100 && e <= 140) ? 1 : 0;
  __syncthreads();
  if (tid == 0){
    int s = 0;
    for (int i=0;i<256;i++) s += cnt[i];
    *p.flag = (s < 192) ? 1 : 0;   // 1 = fp32 inputs
  }
}

// ---------------- prep kernels ----------------
__global__ void prep_idx_k(KParams p){
  int n = blockIdx.x*256 + threadIdx.x;
  if (n >= NN) return;
  int L = 0;
  #pragma unroll
  for (int t=0;t<KCH;t++) L += (p.indice[n*KCH+t] != -1);
  p.len[n] = L;
}

// counting sort by L descending; ntneed[t] = ceil(count(L>t)/128)
__global__ void sort_k(KParams p){
  __shared__ int cnt[17];
  __shared__ int start[17];
  int tid = threadIdx.x;
  if (tid < 17) cnt[tid] = 0;
  __syncthreads();
  for (int n = tid; n < NN; n += 256) atomicAdd(&cnt[p.len[n]], 1);
  __syncthreads();
  if (tid == 0){
    int acc = 0;
    for (int v = 16; v >= 1; --v){ start[v] = acc; acc += cnt[v]; }
    for (int t = 0; t < 16; ++t){
      int need = (t == 0) ? NN : start[t];      // start[t] = count(L > t)
      p.ntneed[t] = (need + 127) >> 7;
    }
  }
  __syncthreads();
  for (int n = tid; n < NN; n += 256){
    int ps = atomicAdd(&start[p.len[n]], 1);
    p.nodeof[ps] = n;
  }
}

__global__ void norm_k(KParams p){
  int i = blockIdx.x*256 + threadIdx.x;
  if (i >= 4207616) return;
  int isf = *p.flag;
  if (i < 2097152)       p.hn[i] = cvt(p.h_tensor, i, isf);
  else if (i < 4194304)  p.cn[i-2097152] = cvt(p.c_tensor, i-2097152, isf);
  else if (i < 4202496){ int j = i-4194304; int gd = j>>10, pc = j&1023;
                         p.biasn[j] = cvt(p.lstm_bias, gd*1024 + ((pc&3)<<8) + (pc>>2), isf); }
  else if (i < 4204544)  p.inithn[i-4202496] = cvt(p.init_h, i-4202496, isf);
  else if (i < 4206592)  p.initcn[i-4204544] = cvt(p.init_c, i-4204544, isf);
  else                   p.wbn[i-4206592] = cvt(p.W_b, i-4206592, isf);
}

__global__ void xperm_k(KParams p){      // xs[sorted] = x[orig]
  int ns = blockIdx.x, u = threadIdx.x;
  int n = p.nodeof[ns];
  p.xs[(size_t)ns*256 + u] = cvt(p.x, (size_t)n*256 + u, *p.flag);
}

__global__ void prep_idx2_k(KParams p){  // idxf/len_s in sorted space
  int ns = blockIdx.x*256 + threadIdx.x;
  if (ns >= NN) return;
  int n = p.nodeof[ns];
  p.len_s[ns] = p.len[n];
  #pragma unroll
  for (int t=0;t<KCH;t++){
    int v = p.indice[n*KCH+t];
    p.idxf[t*NN + ns] = (v != -1) ? v : 0;
  }
}

__global__ void prep_w_k(KParams p){
  int i = blockIdx.x*256 + threadIdx.x;
  int isf = *p.flag;
  if (i < 4194304){                       // wcomb [gd][pc][k]
    int gd = i>>19, pc = (i>>9)&1023, k = i&511;
    int perm = ((pc&3)<<8) + (pc>>2);
    p.wcomb[i] = (k < 256) ? cvt(p.lstm_rec,    (size_t)(gd*256 + k)*1024 + perm, isf)
                           : cvt(p.lstm_kernel, (size_t)(gd*256 + (k-256))*1024 + perm, isf);
  } else if (i < 4980736){                // fcwT2 [g][o][k], k<512 fc_w, k>=512 W_w
    int j = i - 4194304;
    int g = j/196608, rem = j%196608, o = rem/768, k = rem%768;
    p.fcwT2[j] = (k < 512) ? cvt(p.fc_w, (size_t)(g*512 + k)*256 + o, isf)
                           : cvt(p.W_w,  (size_t)(k-512)*1024 + g*256 + o, isf);
  }
}

__global__ void prep_state_k(KParams p){
  int i = blockIdx.x*256 + threadIdx.x;   // 8*4096*256 threads
  int gd = i >> 20;
  p.h_state[i]  = p.inithn[(gd<<8) + (i & 255)];          // [buf0][gd][n][u]
  p.c_stateT[i] = b2f(p.initcn[(gd<<8) + ((i>>12)&255)]); // [gd][u][n]
}

__global__ void fallback_k(float* out){
  int i = blockIdx.x*256 + threadIdx.x;
  out[i] = 1000.0f; out[1048576 + i] = 1000.0f;
}

// ---------------- unified NT GEMM (128x128 tile, bf16 MFMA) ----------------
// LDS layout XOR-swizzled per 8-element chunk (source-permuted staging):
// physical chunk p at (row, p) holds logical chunk p ^ (row&7).
enum { MODE_STAGE=0, MODE_FC0=1, MODE_FC123=2 };

template<int MODE>
__launch_bounds__(256)
__global__ void gemm_k(KParams p, int t)
{
  __shared__ __align__(16) u16 As[2][8192];
  __shared__ __align__(16) u16 Bs[2][8192];
  __shared__ __align__(16) u16 hbuf[(MODE==MODE_STAGE)?128*40:1];
  __shared__ int nidx[(MODE!=MODE_FC123)?128:1];
  __shared__ u16 biasl[(MODE==MODE_STAGE)?128:1];
  __shared__ int Ln[(MODE==MODE_FC0)?8:1];

  const int tid = threadIdx.x;
  const int lane = tid & 63, wv = tid >> 6;
  const int col16 = lane & 15, quad = lane >> 4;
  const int wy = wv >> 1, wx = wv & 1;

  constexpr int K  = (MODE==MODE_STAGE) ? 512 : 768;
  constexpr int KT = K/64;

  int mtile, ntile, gd = 0;
  const u16 *Ap=nullptr, *Bh=nullptr;
  if constexpr (MODE==MODE_STAGE){
    // XCD-pinned swizzle: gd fastest
    int b = blockIdx.x;
    gd = b & 7; mtile = (b>>3) & 7; ntile = b >> 6;
    if (ntile >= p.ntneed[t]) return;   // sorted-by-L early exit
    Ap = p.wcomb + (size_t)gd*1024*512;
    Bh = p.h_state + ((size_t)(t&1)*8 + gd)*NN*256;
  } else if constexpr (MODE==MODE_FC0){
    mtile = blockIdx.x; ntile = blockIdx.y;
  } else {
    mtile = blockIdx.x; ntile = blockIdx.y; gd = blockIdx.z;
  }
  const int rowA = mtile*128;
  const int rowB = ntile*128;

  if constexpr (MODE==MODE_STAGE){
    if (tid < 128){
      int n = rowB + tid;
      int L = p.len_s[n];
      int d = gd & 1;
      int eff = (d && t < L) ? (L-1-t) : t;
      nidx[tid] = p.idxf[eff*NN + n];
      biasl[tid] = p.biasn[gd*1024 + rowA + tid];
    }
    __syncthreads();
  }
  if constexpr (MODE==MODE_FC0){
    if (tid < 128){
      int nl = tid>>4, tt = tid&15;
      nidx[tid] = p.idxf[tt*NN + mtile*8 + nl];
    }
    if (tid < 8) Ln[tid] = p.len_s[mtile*8 + tid];
    __syncthreads();
  }

  // staging with source-side XOR chunk swizzle
  auto stage = [&](int kt, int buf){
    const int kk = kt*64;
    #pragma unroll
    for (int i=0;i<4;i++){
      int ch = wv*4 + i;                  // 16 chunks of 1KB
      int r  = ch*8 + (lane>>3);
      int cs = (((lane&7) ^ (r&7)) << 3); // swizzled source chunk offset
      const u16 *ga, *gb;
      if constexpr (MODE==MODE_STAGE){
        ga = Ap + (size_t)(rowA+r)*512 + kk + cs;
        gb = (kk < 256) ? (Bh + (size_t)(rowB+r)*256 + kk + cs)
                        : (p.hn + (size_t)nidx[r]*256 + (kk-256) + cs);
      } else if constexpr (MODE==MODE_FC0){
        if (kk < 512){
          const u16* Asel = (kk < 256) ? p.y_seq : p.y_seq + (size_t)65536*256;
          ga = Asel + (size_t)(rowA+r)*256 + (kk&255) + cs;
        } else {
          ga = p.xs + (size_t)((rowA+r)>>4)*256 + (kk-512) + cs;
        }
        gb = p.fcwT2 + (size_t)(rowB+r)*768 + kk + cs;
      } else {
        int g = gd + 1;
        if (kk < 512){
          const u16* Asel = p.y_last + (size_t)(g*2 + (kk>=256))*NN*256;
          ga = Asel + (size_t)(rowA+r)*256 + (kk&255) + cs;
        } else {
          ga = p.xs + (size_t)(rowA+r)*256 + (kk-512) + cs;
        }
        gb = p.fcwT2 + (size_t)g*196608 + (size_t)(rowB+r)*768 + kk + cs;
      }
      cp16(ga, &As[buf][ch*512]);
      cp16(gb, &Bs[buf][ch*512]);
    }
  };

  f32x4 acc[4][4] = {};

  stage(0, 0);
  for (int kt = 0; kt < KT; ++kt){
    __syncthreads();                     // drains stage(kt); other buf free
    if (kt+1 < KT) stage(kt+1, (kt+1)&1);  // overlaps with compute below
    const int bsel = kt & 1;
    #pragma unroll
    for (int ks=0; ks<64; ks+=32){
      bf16x8 af[4], bfr[4];
      #pragma unroll
      for (int mf=0; mf<4; mf++){
        int row = wy*64+mf*16+col16;
        int lc  = (ks>>3) + quad;
        af[mf] = *(const bf16x8*)&As[bsel][row*64 + ((lc ^ (row&7))<<3)];
      }
      #pragma unroll
      for (int nf=0; nf<4; nf++){
        int row = wx*64+nf*16+col16;
        int lc  = (ks>>3) + quad;
        bfr[nf] = *(const bf16x8*)&Bs[bsel][row*64 + ((lc ^ (row&7))<<3)];
      }
      #pragma unroll
      for (int mf=0; mf<4; mf++)
        #pragma unroll
        for (int nf=0; nf<4; nf++)
          acc[mf][nf] = __builtin_amdgcn_mfma_f32_16x16x32_bf16(af[mf], bfr[nf], acc[mf][nf], 0, 0, 0);
    }
  }

  if constexpr (MODE==MODE_STAGE){
    // C[row=pcol][col=node]; per lane: 4 regs = gates i,f,g,o of one unit
    const int g = gd >> 1, d = gd & 1;
    const int wbuf = (t+1) & 1;
    #pragma unroll
    for (int nf=0; nf<4; nf++){
      int nc_ = wx*64 + nf*16 + col16;
      int n = rowB + nc_;
      #pragma unroll
      for (int mf=0; mf<4; mf++){
        int lp = wy*64 + mf*16 + quad*4;
        int u  = (rowA + lp) >> 2;
        float zi = acc[mf][nf][0] + b2f(biasl[lp+0]);
        float zf = acc[mf][nf][1] + b2f(biasl[lp+1]);
        float zg = acc[mf][nf][2] + b2f(biasl[lp+2]);
        float zo = acc[mf][nf][3] + b2f(biasl[lp+3]);
        size_t ci = ((size_t)gd*256 + u)*NN + n;
        float cp = p.c_stateT[ci];
        float cn = sigm(zf)*cp + sigm(zi)*tanh_(zg);
        float hn = sigm(zo)*tanh_(cn);
        p.c_stateT[ci] = cn;
        hbuf[nc_*40 + (lp>>2)] = f2b(hn);
      }
    }
    __syncthreads();
    int row = tid >> 1, half = tid & 1;
    int n = rowB + row;
    int u0 = (rowA >> 2) + half*16;
    uint4 v0 = *(const uint4*)&hbuf[row*40 + half*16];
    uint4 v1 = *(const uint4*)&hbuf[row*40 + half*16 + 8];
    u16* hw = p.h_state + (((size_t)wbuf*8 + gd)*NN + n)*256 + u0;
    ((uint4*)hw)[0] = v0; ((uint4*)hw)[1] = v1;
    if (g == 0){
      u16* yw = p.y_seq + ((size_t)d*65536 + (size_t)n*KCH + t)*256 + u0;
      ((uint4*)yw)[0] = v0; ((uint4*)yw)[1] = v1;
    } else if (p.len_s[n] == t+1){
      u16* lw = p.y_last + ((size_t)gd*NN + n)*256 + u0;
      ((uint4*)lw)[0] = v0; ((uint4*)lw)[1] = v1;
    }
  } else if constexpr (MODE==MODE_FC0){
    // acc = f_seq + W_f_x (fused); masked f-branch reduce over t
    #pragma unroll
    for (int mf=0; mf<4; mf++){
      int nl = wy*4 + mf;
      int n  = mtile*8 + nl;
      int L  = Ln[nl];
      #pragma unroll
      for (int nf=0; nf<4; nf++){
        int u = rowB + wx*64 + nf*16 + col16;
        float wb_ = b2f(p.wbn[u]);
        float psum = 0.f;
        #pragma unroll
        for (int r=0;r<4;r++){
          int tt = quad*4 + r;
          if (tt < L){
            int ridx = nidx[nl*16 + tt];
            float cch = b2f(p.cn[(size_t)ridx*256 + u]);
            psum += sigm(acc[mf][nf][r] + wb_) * cch;
          }
        }
        psum += __shfl_xor(psum, 16);
        psum += __shfl_xor(psum, 32);
        if (quad == 0) p.brf[(size_t)n*256 + u] = f2b(psum);
      }
    }
  } else {
    int g = gd + 1;
    #pragma unroll
    for (int mf=0; mf<4; mf++){
      int r0 = rowA + wy*64 + mf*16 + quad*4;
      #pragma unroll
      for (int nf=0; nf<4; nf++){
        int c = rowB + wx*64 + nf*16 + col16;
        float wb_ = b2f(p.wbn[g*256 + c]);
        u16* o = p.fc_outb + (size_t)gd*NN*256 + (size_t)r0*256 + c;
        #pragma unroll
        for (int r=0;r<4;r++) o[(size_t)r*256] = f2b(acc[mf][nf][r] + wb_);
      }
    }
  }
}

// ---------------- final combine (fp32 output, un-permute) ----------------
__global__ void final_k(KParams p){
  int i = blockIdx.x*256 + threadIdx.x;  // i = sorted_n*256+u
  int ns = i >> 8, u = i & 255;
  int n = p.nodeof[ns];
  float bf_ = b2f(p.brf[i]);
  float bi = sigm (b2f(p.fc_outb[i]));
  float bu = tanh_(b2f(p.fc_outb[1048576 + i]));
  float bo = sigm (b2f(p.fc_outb[2097152 + i]));
  float nc = bi*bu + bf_;
  float nh = bo*tanh_(nc);
  p.outp[(size_t)n*256 + u] = nh;
  p.outp[1048576 + (size_t)n*256 + u] = nc;
}

extern "C" void kernel_launch(void* const* d_in, const int* in_sizes, int n_in,
                              void* d_out, int out_size, void* d_ws, size_t ws_size,
                              hipStream_t stream) {
  if (ws_size < WS_NEEDED){
    fallback_k<<<4096, 256, 0, stream>>>((float*)d_out);
    return;
  }
  KParams p;
  p.x          = d_in[0];
  p.h_tensor   = d_in[1];
  p.c_tensor   = d_in[2];
  p.indice     = (const int*)d_in[3];
  p.W_w        = d_in[4];
  p.W_b        = d_in[5];
  p.lstm_kernel= d_in[6];
  p.lstm_rec   = d_in[7];
  p.lstm_bias  = d_in[8];
  p.init_h     = d_in[9];
  p.init_c     = d_in[10];
  p.fc_w       = d_in[11];
  char* w = (char*)d_ws;
  p.wcomb   = (u16*)  (w + OFF_WCOMB);
  p.fcwT2   = (u16*)  (w + OFF_FCWT);
  p.h_state = (u16*)  (w + OFF_HST);
  p.c_stateT= (float*)(w + OFF_CST);
  p.y_seq   = (u16*)  (w + OFF_YSEQ);
  p.y_last  = (u16*)  (w + OFF_YLAST);
  p.brf     = (u16*)  (w + OFF_BRF);
  p.fc_outb = (u16*)  (w + OFF_FCO);
  p.xs      = (u16*)  (w + OFF_XS);
  p.hn      = (u16*)  (w + OFF_HN);
  p.cn      = (u16*)  (w + OFF_CN);
  p.biasn   = (u16*)  (w + OFF_BIASN);
  p.inithn  = (u16*)  (w + OFF_IHN);
  p.initcn  = (u16*)  (w + OFF_ICN);
  p.wbn     = (u16*)  (w + OFF_WBN);
  p.idxf    = (int*)  (w + OFF_IDX);
  p.len     = (int*)  (w + OFF_LEN);
  p.flag    = (int*)  (w + OFF_FLAG);
  p.nodeof  = (int*)  (w + OFF_NODEOF);
  p.len_s   = (int*)  (w + OFF_LENS);
  p.ntneed  = (int*)  (w + OFF_NTN);
  p.outp    = (float*)d_out;

  detect_k    <<<1,     256, 0, stream>>>(p);
  prep_idx_k  <<<16,    256, 0, stream>>>(p);
  sort_k      <<<1,     256, 0, stream>>>(p);
  norm_k      <<<16436, 256, 0, stream>>>(p);
  xperm_k     <<<4096,  256, 0, stream>>>(p);
  prep_idx2_k <<<16,    256, 0, stream>>>(p);
  prep_w_k    <<<19456, 256, 0, stream>>>(p);
  prep_state_k<<<32768, 256, 0, stream>>>(p);

  for (int t = 0; t < KCH; ++t)
    gemm_k<MODE_STAGE><<<2048, 256, 0, stream>>>(p, t); // swizzled LDS + dbuf pipeline

  gemm_k<MODE_FC0>  <<<dim3(512,2), 256, 0, stream>>>(p, 0);   // f fc (+W_f_x) + masked reduce
  gemm_k<MODE_FC123><<<dim3(32,2,3), 256, 0, stream>>>(p, 0);  // i,u,o last-step fc (+W_x)

  final_k<<<4096, 256, 0, stream>>>(p);
}

// Round 8
// 828.068 us; speedup vs baseline: 2.5239x; 1.0970x over previous
//
#include <hip/hip_runtime.h>
#include <stdint.h>

typedef __bf16 bf16x8 __attribute__((ext_vector_type(8)));
typedef float  f32x4  __attribute__((ext_vector_type(4)));
typedef unsigned short u16;
typedef unsigned int   u32;

#define NN   4096      // nodes
#define KCH  16        // max children
#define RR   8192      // rows in h/c tensors

// ---------------- workspace layout (bytes) ----------------
static constexpr size_t OFF_WCOMB = 0;          //  8 gd x 1024 pc x 512 k bf16
static constexpr size_t OFF_FCWT  = 8388608;    //  4 g x 256 o x 768 k bf16
static constexpr size_t OFF_HST   = 9961472;    //  2 buf x 8 gd x 4096 n x 256 u bf16 (sorted n)
static constexpr size_t OFF_CST   = 43515904;   //  8 gd x 256 u x 4096 n fp32 (sorted)
static constexpr size_t OFF_YSEQ  = 77070336;   //  2 d x (4096 n x 16 t) x 256 u bf16 (sorted)
static constexpr size_t OFF_YLAST = 144179200;  //  8 gd x 4096 n x 256 u bf16 (sorted, gd>=2 used)
static constexpr size_t OFF_BRF   = 160956416;  //  4096 x 256 bf16 (sorted)
static constexpr size_t OFF_FCO   = 163053568;  //  3 x 4096 x 256 bf16 (sorted)
static constexpr size_t OFF_XS    = 169345024;  //  4096 x 256 bf16 (sorted)
static constexpr size_t OFF_HN    = 171442176;  //  8192 x 256 bf16
static constexpr size_t OFF_CN    = 175636480;  //  8192 x 256 bf16
static constexpr size_t OFF_BIASN = 179830784;  //  8 gd x 1024 pc bf16
static constexpr size_t OFF_IHN   = 179847168;  //  8 x 256 bf16
static constexpr size_t OFF_ICN   = 179851264;  //  8 x 256 bf16
static constexpr size_t OFF_WBN   = 179855360;  //  1024 bf16
static constexpr size_t OFF_IDX   = 179857408;  //  [16 t][4096 sorted n] int32
static constexpr size_t OFF_LEN   = 180119552;  //  4096 int32 (orig order)
static constexpr size_t OFF_FLAG  = 180135936;  //  int
static constexpr size_t OFF_NODEOF= 180136000;  //  4096 int32
static constexpr size_t OFF_LENS  = 180152384;  //  4096 int32 (sorted)
static constexpr size_t OFF_NTN   = 180168768;  //  16 int32
static constexpr size_t WS_NEEDED = 180168832;  //  <= 180371456 (known to fit)

struct KParams {
  const void *x, *h_tensor, *c_tensor, *W_w, *W_b, *lstm_kernel, *lstm_rec,
             *lstm_bias, *init_h, *init_c, *fc_w;
  const int *indice;
  u16 *wcomb, *fcwT2, *h_state, *y_seq, *y_last, *brf, *fc_outb,
      *xs, *hn, *cn, *biasn, *inithn, *initcn, *wbn;
  float *c_stateT;
  int *idxf, *len, *flag, *nodeof, *len_s, *ntneed;
  float *outp;                       // OUTPUT IS FLOAT32 (established round 3)
};

__device__ __forceinline__ float b2f(u16 u){ union{u32 i;float f;}v; v.i=((u32)u)<<16; return v.f; }
__device__ __forceinline__ u16  f2b(float f){ union{float f;u32 i;}v; v.f=f; u32 r=v.i+0x7FFFu+((v.i>>16)&1u); return (u16)(r>>16); }
__device__ __forceinline__ float sigm(float x){ return 1.0f/(1.0f+__expf(-x)); }
__device__ __forceinline__ float tanh_(float x){ return 2.0f/(1.0f+__expf(-2.0f*x)) - 1.0f; }
__device__ __forceinline__ u16  cvt(const void* q, size_t i, int isf){
  return isf ? f2b(((const float*)q)[i]) : ((const u16*)q)[i];
}
__device__ __forceinline__ void cp16(const u16* g, u16* l){
  __builtin_amdgcn_global_load_lds((const __attribute__((address_space(1))) u32*)g,
                                   (__attribute__((address_space(3))) u32*)l, 16, 0, 0);
}

// ---------------- dtype detector (fp32 vs bf16 inputs) ----------------
__global__ void detect_k(KParams p){
  __shared__ int cnt[256];
  int tid = threadIdx.x;
  u16 u = ((const u16*)p.x)[2*tid];
  int e = (u >> 7) & 0xFF;
  cnt[tid] = (u != 0 && e >= 100 && e <= 140) ? 1 : 0;
  __syncthreads();
  if (tid == 0){
    int s = 0;
    for (int i=0;i<256;i++) s += cnt[i];
    *p.flag = (s < 192) ? 1 : 0;   // 1 = fp32 inputs
  }
}

// ---------------- prep kernels ----------------
__global__ void prep_idx_k(KParams p){
  int n = blockIdx.x*256 + threadIdx.x;
  if (n >= NN) return;
  int L = 0;
  #pragma unroll
  for (int t=0;t<KCH;t++) L += (p.indice[n*KCH+t] != -1);
  p.len[n] = L;
}

// counting sort by L descending; ntneed[t] = ceil(count(L>t)/128)
__global__ void sort_k(KParams p){
  __shared__ int cnt[17];
  __shared__ int start[17];
  int tid = threadIdx.x;
  if (tid < 17) cnt[tid] = 0;
  __syncthreads();
  for (int n = tid; n < NN; n += 256) atomicAdd(&cnt[p.len[n]], 1);
  __syncthreads();
  if (tid == 0){
    int acc = 0;
    for (int v = 16; v >= 1; --v){ start[v] = acc; acc += cnt[v]; }
    for (int t = 0; t < 16; ++t){
      int need = (t == 0) ? NN : start[t];      // start[t] = count(L > t)
      p.ntneed[t] = (need + 127) >> 7;
    }
  }
  __syncthreads();
  for (int n = tid; n < NN; n += 256){
    int ps = atomicAdd(&start[p.len[n]], 1);
    p.nodeof[ps] = n;
  }
}

__global__ void norm_k(KParams p){
  int i = blockIdx.x*256 + threadIdx.x;
  if (i >= 4207616) return;
  int isf = *p.flag;
  if (i < 2097152)       p.hn[i] = cvt(p.h_tensor, i, isf);
  else if (i < 4194304)  p.cn[i-2097152] = cvt(p.c_tensor, i-2097152, isf);
  else if (i < 4202496){ int j = i-4194304; int gd = j>>10, pc = j&1023;
                         p.biasn[j] = cvt(p.lstm_bias, gd*1024 + ((pc&3)<<8) + (pc>>2), isf); }
  else if (i < 4204544)  p.inithn[i-4202496] = cvt(p.init_h, i-4202496, isf);
  else if (i < 4206592)  p.initcn[i-4204544] = cvt(p.init_c, i-4204544, isf);
  else                   p.wbn[i-4206592] = cvt(p.W_b, i-4206592, isf);
}

__global__ void xperm_k(KParams p){      // xs[sorted] = x[orig]
  int ns = blockIdx.x, u = threadIdx.x;
  int n = p.nodeof[ns];
  p.xs[(size_t)ns*256 + u] = cvt(p.x, (size_t)n*256 + u, *p.flag);
}

__global__ void prep_idx2_k(KParams p){  // idxf/len_s in sorted space
  int ns = blockIdx.x*256 + threadIdx.x;
  if (ns >= NN) return;
  int n = p.nodeof[ns];
  p.len_s[ns] = p.len[n];
  #pragma unroll
  for (int t=0;t<KCH;t++){
    int v = p.indice[n*KCH+t];
    p.idxf[t*NN + ns] = (v != -1) ? v : 0;
  }
}

__global__ void prep_w_k(KParams p){
  int i = blockIdx.x*256 + threadIdx.x;
  int isf = *p.flag;
  if (i < 4194304){                       // wcomb [gd][pc][k]
    int gd = i>>19, pc = (i>>9)&1023, k = i&511;
    int perm = ((pc&3)<<8) + (pc>>2);
    p.wcomb[i] = (k < 256) ? cvt(p.lstm_rec,    (size_t)(gd*256 + k)*1024 + perm, isf)
                           : cvt(p.lstm_kernel, (size_t)(gd*256 + (k-256))*1024 + perm, isf);
  } else if (i < 4980736){                // fcwT2 [g][o][k], k<512 fc_w, k>=512 W_w
    int j = i - 4194304;
    int g = j/196608, rem = j%196608, o = rem/768, k = rem%768;
    p.fcwT2[j] = (k < 512) ? cvt(p.fc_w, (size_t)(g*512 + k)*256 + o, isf)
                           : cvt(p.W_w,  (size_t)(k-512)*1024 + g*256 + o, isf);
  }
}

__global__ void prep_state_k(KParams p){
  int i = blockIdx.x*256 + threadIdx.x;   // 8*4096*256 threads
  int gd = i >> 20;
  p.h_state[i]  = p.inithn[(gd<<8) + (i & 255)];          // [buf0][gd][n][u]
  p.c_stateT[i] = b2f(p.initcn[(gd<<8) + ((i>>12)&255)]); // [gd][u][n]
}

__global__ void fallback_k(float* out){
  int i = blockIdx.x*256 + threadIdx.x;
  out[i] = 1000.0f; out[1048576 + i] = 1000.0f;
}

// ---------------- stage kernel: 512 threads, 256x128 tile ----------------
// LDS XOR-swizzled per 8-elem chunk (source-permuted staging). Single-buffer,
// hbuf aliased onto As after the K-loop. 2 blocks/CU (16 waves).
__global__ __launch_bounds__(512, 4) void stage512_k(KParams p, int t)
{
  __shared__ __align__(16) u16 As[16384];   // 256 pcol-rows x 64 k (reused as hbuf)
  __shared__ __align__(16) u16 Bs[8192];    // 128 node-rows x 64 k
  __shared__ int nidx[128];
  __shared__ u16 biasl[256];

  const int tid = threadIdx.x;
  const int lane = tid & 63, wv = tid >> 6;   // 8 waves
  const int col16 = lane & 15, quad = lane >> 4;
  const int wy = wv >> 1, wx = wv & 1;        // wy: 4 M-slices, wx: 2 N-slices

  const int b = blockIdx.x;
  const int gd = b & 7, mtile = (b>>3) & 3, ntile = b >> 5;  // gd fastest -> XCD pin
  if (ntile >= p.ntneed[t]) return;            // sorted-by-L early exit
  const u16* __restrict__ Ap = p.wcomb + (size_t)gd*524288;
  const u16* __restrict__ Bh = p.h_state + ((size_t)(t&1)*8 + gd)*NN*256;
  const int rowA = mtile*256;                  // pcol base
  const int rowB = ntile*128;                  // node base
  const int d = gd & 1;

  if (tid < 128){
    int n = rowB + tid;
    int L = p.len_s[n];
    int eff = (d && t < L) ? (L-1-t) : t;
    nidx[tid] = p.idxf[eff*NN + n];
  }
  if (tid < 256) biasl[tid] = p.biasn[gd*1024 + rowA + tid];
  __syncthreads();

  f32x4 acc[4][4] = {};

  for (int kt = 0; kt < 8; ++kt){
    const int kk = kt*64;
    #pragma unroll
    for (int i=0;i<4;i++){                     // A: 32 x 1KB chunks
      int ch = wv*4 + i;
      int r  = ch*8 + (lane>>3);
      int cs = (((lane&7) ^ (r&7)) << 3);
      cp16(Ap + (size_t)(rowA+r)*512 + kk + cs, &As[ch*512]);
    }
    #pragma unroll
    for (int i=0;i<2;i++){                     // B: 16 x 1KB chunks
      int ch = wv*2 + i;
      int r  = ch*8 + (lane>>3);
      int cs = (((lane&7) ^ (r&7)) << 3);
      const u16* gb = (kk < 256) ? (Bh + (size_t)(rowB+r)*256 + kk + cs)
                                 : (p.hn + (size_t)nidx[r]*256 + (kk-256) + cs);
      cp16(gb, &Bs[ch*512]);
    }
    __syncthreads();
    #pragma unroll
    for (int ks=0; ks<64; ks+=32){
      bf16x8 af[4], bfr[4];
      #pragma unroll
      for (int mf=0; mf<4; mf++){
        int row = wy*64+mf*16+col16;
        int lc  = (ks>>3) + quad;
        af[mf] = *(const bf16x8*)&As[row*64 + ((lc ^ (row&7))<<3)];
      }
      #pragma unroll
      for (int nf=0; nf<4; nf++){
        int row = wx*64+nf*16+col16;
        int lc  = (ks>>3) + quad;
        bfr[nf] = *(const bf16x8*)&Bs[row*64 + ((lc ^ (row&7))<<3)];
      }
      #pragma unroll
      for (int mf=0; mf<4; mf++)
        #pragma unroll
        for (int nf=0; nf<4; nf++)
          acc[mf][nf] = __builtin_amdgcn_mfma_f32_16x16x32_bf16(af[mf], bfr[nf], acc[mf][nf], 0, 0, 0);
    }
    __syncthreads();
  }

  // epilogue: LSTM cell; h -> hbuf (aliased on As, stride 72 breaks conflicts)
  u16* hbuf = As;
  const int g = gd >> 1;
  const int wbuf = (t+1) & 1;
  #pragma unroll
  for (int nf=0; nf<4; nf++){
    int nc_ = wx*64 + nf*16 + col16;
    int n = rowB + nc_;
    #pragma unroll
    for (int mf=0; mf<4; mf++){
      int lp = wy*64 + mf*16 + quad*4;
      int u  = (rowA + lp) >> 2;
      float zi = acc[mf][nf][0] + b2f(biasl[lp+0]);
      float zf = acc[mf][nf][1] + b2f(biasl[lp+1]);
      float zg = acc[mf][nf][2] + b2f(biasl[lp+2]);
      float zo = acc[mf][nf][3] + b2f(biasl[lp+3]);
      size_t ci = ((size_t)gd*256 + u)*NN + n;
      float cp = p.c_stateT[ci];
      float cn = sigm(zf)*cp + sigm(zi)*tanh_(zg);
      float hn = sigm(zo)*tanh_(cn);
      p.c_stateT[ci] = cn;
      hbuf[nc_*72 + (lp>>2)] = f2b(hn);
    }
  }
  __syncthreads();
  // writeout: 128 node-rows x 64 units (this block's pcol/4 slice)
  int row = tid >> 2, part = tid & 3;
  int n = rowB + row;
  int u0 = (rowA >> 2) + part*16;
  uint4 v0 = *(const uint4*)&hbuf[row*72 + part*16];
  uint4 v1 = *(const uint4*)&hbuf[row*72 + part*16 + 8];
  u16* hw = p.h_state + (((size_t)wbuf*8 + gd)*NN + n)*256 + u0;
  ((uint4*)hw)[0] = v0; ((uint4*)hw)[1] = v1;
  if (g == 0){
    u16* yw = p.y_seq + ((size_t)d*65536 + (size_t)n*KCH + t)*256 + u0;
    ((uint4*)yw)[0] = v0; ((uint4*)yw)[1] = v1;
  } else if (p.len_s[n] == t+1){
    u16* lw = p.y_last + ((size_t)gd*NN + n)*256 + u0;
    ((uint4*)lw)[0] = v0; ((uint4*)lw)[1] = v1;
  }
}

// ---------------- FC GEMMs (128x128 tile, K=768, dbuf + swizzle) ----------------
enum { MODE_FC0=0, MODE_FC123=1 };

template<int MODE>
__launch_bounds__(256)
__global__ void gemm_k(KParams p)
{
  __shared__ __align__(16) u16 As[2][8192];
  __shared__ __align__(16) u16 Bs[2][8192];
  __shared__ int nidx[(MODE==MODE_FC0)?128:1];
  __shared__ int Ln[(MODE==MODE_FC0)?8:1];

  const int tid = threadIdx.x;
  const int lane = tid & 63, wv = tid >> 6;
  const int col16 = lane & 15, quad = lane >> 4;
  const int wy = wv >> 1, wx = wv & 1;

  constexpr int KT = 12;   // K=768

  int mtile = blockIdx.x, ntile = blockIdx.y, gd = blockIdx.z;
  const int rowA = mtile*128;
  const int rowB = ntile*128;

  if constexpr (MODE==MODE_FC0){
    if (tid < 128){
      int nl = tid>>4, tt = tid&15;
      nidx[tid] = p.idxf[tt*NN + mtile*8 + nl];
    }
    if (tid < 8) Ln[tid] = p.len_s[mtile*8 + tid];
    __syncthreads();
  }

  auto stage = [&](int kt, int buf){
    const int kk = kt*64;
    #pragma unroll
    for (int i=0;i<4;i++){
      int ch = wv*4 + i;
      int r  = ch*8 + (lane>>3);
      int cs = (((lane&7) ^ (r&7)) << 3);
      const u16 *ga, *gb;
      if constexpr (MODE==MODE_FC0){
        if (kk < 512){
          const u16* Asel = (kk < 256) ? p.y_seq : p.y_seq + (size_t)65536*256;
          ga = Asel + (size_t)(rowA+r)*256 + (kk&255) + cs;
        } else {
          ga = p.xs + (size_t)((rowA+r)>>4)*256 + (kk-512) + cs;
        }
        gb = p.fcwT2 + (size_t)(rowB+r)*768 + kk + cs;
      } else {
        int g = gd + 1;
        if (kk < 512){
          const u16* Asel = p.y_last + (size_t)(g*2 + (kk>=256))*NN*256;
          ga = Asel + (size_t)(rowA+r)*256 + (kk&255) + cs;
        } else {
          ga = p.xs + (size_t)(rowA+r)*256 + (kk-512) + cs;
        }
        gb = p.fcwT2 + (size_t)g*196608 + (size_t)(rowB+r)*768 + kk + cs;
      }
      cp16(ga, &As[buf][ch*512]);
      cp16(gb, &Bs[buf][ch*512]);
    }
  };

  f32x4 acc[4][4] = {};

  stage(0, 0);
  for (int kt = 0; kt < KT; ++kt){
    __syncthreads();
    if (kt+1 < KT) stage(kt+1, (kt+1)&1);
    const int bsel = kt & 1;
    #pragma unroll
    for (int ks=0; ks<64; ks+=32){
      bf16x8 af[4], bfr[4];
      #pragma unroll
      for (int mf=0; mf<4; mf++){
        int row = wy*64+mf*16+col16;
        int lc  = (ks>>3) + quad;
        af[mf] = *(const bf16x8*)&As[bsel][row*64 + ((lc ^ (row&7))<<3)];
      }
      #pragma unroll
      for (int nf=0; nf<4; nf++){
        int row = wx*64+nf*16+col16;
        int lc  = (ks>>3) + quad;
        bfr[nf] = *(const bf16x8*)&Bs[bsel][row*64 + ((lc ^ (row&7))<<3)];
      }
      #pragma unroll
      for (int mf=0; mf<4; mf++)
        #pragma unroll
        for (int nf=0; nf<4; nf++)
          acc[mf][nf] = __builtin_amdgcn_mfma_f32_16x16x32_bf16(af[mf], bfr[nf], acc[mf][nf], 0, 0, 0);
    }
  }

  if constexpr (MODE==MODE_FC0){
    // acc = f_seq + W_f_x (fused); masked f-branch reduce over t
    #pragma unroll
    for (int mf=0; mf<4; mf++){
      int nl = wy*4 + mf;
      int n  = mtile*8 + nl;
      int L  = Ln[nl];
      #pragma unroll
      for (int nf=0; nf<4; nf++){
        int u = rowB + wx*64 + nf*16 + col16;
        float wb_ = b2f(p.wbn[u]);
        float psum = 0.f;
        #pragma unroll
        for (int r=0;r<4;r++){
          int tt = quad*4 + r;
          if (tt < L){
            int ridx = nidx[nl*16 + tt];
            float cch = b2f(p.cn[(size_t)ridx*256 + u]);
            psum += sigm(acc[mf][nf][r] + wb_) * cch;
          }
        }
        psum += __shfl_xor(psum, 16);
        psum += __shfl_xor(psum, 32);
        if (quad == 0) p.brf[(size_t)n*256 + u] = f2b(psum);
      }
    }
  } else {
    int g = gd + 1;
    #pragma unroll
    for (int mf=0; mf<4; mf++){
      int r0 = rowA + wy*64 + mf*16 + quad*4;
      #pragma unroll
      for (int nf=0; nf<4; nf++){
        int c = rowB + wx*64 + nf*16 + col16;
        float wb_ = b2f(p.wbn[g*256 + c]);
        u16* o = p.fc_outb + (size_t)gd*NN*256 + (size_t)r0*256 + c;
        #pragma unroll
        for (int r=0;r<4;r++) o[(size_t)r*256] = f2b(acc[mf][nf][r] + wb_);
      }
    }
  }
}

// ---------------- final combine (fp32 output, un-permute) ----------------
__global__ void final_k(KParams p){
  int i = blockIdx.x*256 + threadIdx.x;  // i = sorted_n*256+u
  int ns = i >> 8, u = i & 255;
  int n = p.nodeof[ns];
  float bf_ = b2f(p.brf[i]);
  float bi = sigm (b2f(p.fc_outb[i]));
  float bu = tanh_(b2f(p.fc_outb[1048576 + i]));
  float bo = sigm (b2f(p.fc_outb[2097152 + i]));
  float nc = bi*bu + bf_;
  float nh = bo*tanh_(nc);
  p.outp[(size_t)n*256 + u] = nh;
  p.outp[1048576 + (size_t)n*256 + u] = nc;
}

extern "C" void kernel_launch(void* const* d_in, const int* in_sizes, int n_in,
                              void* d_out, int out_size, void* d_ws, size_t ws_size,
                              hipStream_t stream) {
  if (ws_size < WS_NEEDED){
    fallback_k<<<4096, 256, 0, stream>>>((float*)d_out);
    return;
  }
  KParams p;
  p.x          = d_in[0];
  p.h_tensor   = d_in[1];
  p.c_tensor   = d_in[2];
  p.indice     = (const int*)d_in[3];
  p.W_w        = d_in[4];
  p.W_b        = d_in[5];
  p.lstm_kernel= d_in[6];
  p.lstm_rec   = d_in[7];
  p.lstm_bias  = d_in[8];
  p.init_h     = d_in[9];
  p.init_c     = d_in[10];
  p.fc_w       = d_in[11];
  char* w = (char*)d_ws;
  p.wcomb   = (u16*)  (w + OFF_WCOMB);
  p.fcwT2   = (u16*)  (w + OFF_FCWT);
  p.h_state = (u16*)  (w + OFF_HST);
  p.c_stateT= (float*)(w + OFF_CST);
  p.y_seq   = (u16*)  (w + OFF_YSEQ);
  p.y_last  = (u16*)  (w + OFF_YLAST);
  p.brf     = (u16*)  (w + OFF_BRF);
  p.fc_outb = (u16*)  (w + OFF_FCO);
  p.xs      = (u16*)  (w + OFF_XS);
  p.hn      = (u16*)  (w + OFF_HN);
  p.cn      = (u16*)  (w + OFF_CN);
  p.biasn   = (u16*)  (w + OFF_BIASN);
  p.inithn  = (u16*)  (w + OFF_IHN);
  p.initcn  = (u16*)  (w + OFF_ICN);
  p.wbn     = (u16*)  (w + OFF_WBN);
  p.idxf    = (int*)  (w + OFF_IDX);
  p.len     = (int*)  (w + OFF_LEN);
  p.flag    = (int*)  (w + OFF_FLAG);
  p.nodeof  = (int*)  (w + OFF_NODEOF);
  p.len_s   = (int*)  (w + OFF_LENS);
  p.ntneed  = (int*)  (w + OFF_NTN);
  p.outp    = (float*)d_out;

  detect_k    <<<1,     256, 0, stream>>>(p);
  prep_idx_k  <<<16,    256, 0, stream>>>(p);
  sort_k      <<<1,     256, 0, stream>>>(p);
  norm_k      <<<16436, 256, 0, stream>>>(p);
  xperm_k     <<<4096,  256, 0, stream>>>(p);
  prep_idx2_k <<<16,    256, 0, stream>>>(p);
  prep_w_k    <<<19456, 256, 0, stream>>>(p);
  prep_state_k<<<32768, 256, 0, stream>>>(p);

  for (int t = 0; t < KCH; ++t)
    stage512_k<<<1024, 512, 0, stream>>>(p, t);  // 256x128 tile, 8 waves/block

  gemm_k<MODE_FC0>  <<<dim3(512,2,1), 256, 0, stream>>>(p);   // f fc (+W_f_x) + masked reduce
  gemm_k<MODE_FC123><<<dim3(32,2,3),  256, 0, stream>>>(p);   // i,u,o last-step fc (+W_x)

  final_k<<<4096, 256, 0, stream>>>(p);
}